// Round 5
// baseline (103.153 us; speedup 1.0000x reference)
//
#include <hip/hip_runtime.h>
#include <hip/hip_bf16.h>
#include <math.h>

#define NG  256
#define NN  64
#define KK  24
#define HID 128
#define KP  136   // bf16 LDS row stride (shorts): 272B
#define FP  132   // fp32 LDS row stride (floats)
#define DP  68    // dmat row stride (floats)
#define FRAG 512                 // shorts per fragment (64 lanes x 8)
#define SLAB (4*8*2*FRAG)        // 32768 shorts per weight slab (tn x ks x hl x frag)
#define IMG_BYTES (3*SLAB*2)     // 196608 B

typedef __attribute__((ext_vector_type(8)))  short bf16x8;
typedef __attribute__((ext_vector_type(4)))  float f32x4;
typedef __attribute__((ext_vector_type(16))) float f32x16;

__device__ __forceinline__ float elu1(float x){ return x > 0.f ? x : (expf(x)-1.f); }

__device__ __forceinline__ short bf_hi(float x){
    __hip_bfloat16 h = __float2bfloat16(x);
    return *(short*)&h;
}
__device__ __forceinline__ float bf_f(short s){
    __hip_bfloat16 h = *(__hip_bfloat16*)&s;
    return __bfloat162float(h);
}

// ---- prep: weights -> MFMA-fragment-ordered bf16 hi/lo images in d_ws ----
// addr(s,tn,ks,hl,lane,j) = s*SLAB + ((tn*8+ks)*2+hl)*FRAG + lane*8 + j
// value = W[k][n], n = tn*32+(lane&31), k = ks*16+(lane>>5)*8+j
// s=0: W2 ; s=1: Wc[0:128) (U) ; s=2: Wc[128:256) (V)
extern "C" __global__ void prep_kernel(const float* __restrict__ W2,
                                       const float* __restrict__ Wc,
                                       short* __restrict__ img)
{
    int t = blockIdx.x * 256 + threadIdx.x;    // (s,tn,ks,lane)
    if (t >= 3*4*8*64) return;
    const int lane = t & 63;
    const int ks   = (t >> 6) & 7;
    const int tn   = (t >> 9) & 3;
    const int s    = t >> 11;
    const int n     = tn*32 + (lane & 31);
    const int kbase = ks*16 + (lane >> 5)*8;
    bf16x8 hv, lv;
    #pragma unroll
    for (int j = 0; j < 8; ++j){
        const int k = kbase + j;
        float w = (s == 0) ? W2[k*HID + n]
                : (s == 1) ? Wc[k*HID + n]
                           : Wc[(k + HID)*HID + n];
        short h = bf_hi(w);
        hv[j] = h;
        lv[j] = bf_hi(w - bf_f(h));
    }
    short* dst = img + s*SLAB + ((tn*8 + ks)*2)*FRAG + lane*8;
    *(bf16x8*)(dst)        = hv;
    *(bf16x8*)(dst + FRAG) = lv;
}

// 32x32-tile 3-pass GEMM: A = features (LDS hi/lo), B = weights (global frag img, or gather fallback)
__device__ __forceinline__ f32x16 gemmW(const short* __restrict__ fbhi,
                                        const short* __restrict__ fblo,
                                        const short* __restrict__ imgSlab,
                                        const float* __restrict__ Wg, int rowoff,
                                        int use_img, int tm, int tn, int lane)
{
    f32x16 c;
    #pragma unroll
    for (int i = 0; i < 16; ++i) c[i] = 0.f;
    const int arow = tm*32 + (lane & 31);
    const int ko   = (lane >> 5) * 8;
    const int col  = tn*32 + (lane & 31);
    #pragma unroll
    for (int ks = 0; ks < 8; ++ks){
        bf16x8 ah = *(const bf16x8*)(fbhi + arow*KP + ks*16 + ko);
        bf16x8 al = *(const bf16x8*)(fblo + arow*KP + ks*16 + ko);
        bf16x8 bh, bl;
        if (use_img){
            const short* p = imgSlab + ((tn*8 + ks)*2)*FRAG + lane*8;
            bh = *(const bf16x8*)(p);
            bl = *(const bf16x8*)(p + FRAG);
        } else {
            #pragma unroll
            for (int j = 0; j < 8; ++j){
                float w = Wg[(rowoff + ks*16 + ko + j)*HID + col];
                short h = bf_hi(w);
                bh[j] = h;
                bl[j] = bf_hi(w - bf_f(h));
            }
        }
        c = __builtin_amdgcn_mfma_f32_32x32x16_bf16(ah, bh, c, 0,0,0);
        c = __builtin_amdgcn_mfma_f32_32x32x16_bf16(ah, bl, c, 0,0,0);
        c = __builtin_amdgcn_mfma_f32_32x32x16_bf16(al, bh, c, 0,0,0);
    }
    return c;
}

extern "C" __global__ void __launch_bounds__(512, 1)
dgcnn_kernel(const float* __restrict__ x_pf,
             const float* __restrict__ W1, const float* __restrict__ b1,
             const float* __restrict__ W2, const float* __restrict__ b2,
             const float* __restrict__ Wc, const float* __restrict__ bc,
             const float* __restrict__ Wo1, const float* __restrict__ bo1,
             const float* __restrict__ Wo2, const float* __restrict__ bo2,
             const float* __restrict__ Wo3, const float* __restrict__ bo3,
             const float* __restrict__ Wo4, const float* __restrict__ bo4,
             const short* __restrict__ img, int use_img,
             float* __restrict__ out)
{
    __shared__ __align__(16) short fbhi[NN*KP];   // 17408 B: features hi / then U hi
    __shared__ __align__(16) short fblo[NN*KP];   // 17408 B: features lo / then U lo
    __shared__ __align__(16) float Vbuf[NN*FP];   // 33792 B: dmat early, V fp32 late, head scratch
    __shared__ int   knn[NN*KK];                  // 6144 B
    __shared__ float sq[NN];                      // 256 B
    // total 75008 B

    const int tid  = threadIdx.x;
    const int g    = blockIdx.x;
    const int lane = tid & 63;
    const int wv   = tid >> 6;          // 0..7
    const int hq   = tid & 31;
    const int ngp  = tid >> 5;          // 0..15
    const int h0   = hq * 4;
    const int n0   = ngp * 4;
    const int tm   = wv & 1;
    const int tn   = wv >> 1;

    float* dmat = Vbuf;                 // 64 x DP inside Vbuf (dead before V written)

    if (tid < NN) out[NG*8 + g*NN + tid] = (float)g;

    // ---- W1: h1 = elu(x@W1+b1) -> hi/lo directly ----
    {
        float acc[4][4];
        float4 bv = *(const float4*)(b1 + h0);
        #pragma unroll
        for (int r = 0; r < 4; ++r){ acc[r][0]=bv.x; acc[r][1]=bv.y; acc[r][2]=bv.z; acc[r][3]=bv.w; }
        #pragma unroll
        for (int f = 0; f < 15; ++f){
            float4 w = *(const float4*)(W1 + f*HID + h0);
            #pragma unroll
            for (int r = 0; r < 4; ++r){
                float xv = x_pf[g*NN*15 + (n0 + r)*15 + f];
                acc[r][0] += xv*w.x; acc[r][1] += xv*w.y;
                acc[r][2] += xv*w.z; acc[r][3] += xv*w.w;
            }
        }
        #pragma unroll
        for (int r = 0; r < 4; ++r){
            short4 hv, lv;
            float v0 = elu1(acc[r][0]), v1 = elu1(acc[r][1]), v2 = elu1(acc[r][2]), v3 = elu1(acc[r][3]);
            hv.x = bf_hi(v0); lv.x = bf_hi(v0 - bf_f(hv.x));
            hv.y = bf_hi(v1); lv.y = bf_hi(v1 - bf_f(hv.y));
            hv.z = bf_hi(v2); lv.z = bf_hi(v2 - bf_f(hv.z));
            hv.w = bf_hi(v3); lv.w = bf_hi(v3 - bf_f(hv.w));
            *(short4*)(fbhi + (n0 + r)*KP + h0) = hv;
            *(short4*)(fblo + (n0 + r)*KP + h0) = lv;
        }
    }
    __syncthreads();

    // ---- W2 GEMM: feat = elu(h1@W2 + b2) ----
    {
        f32x16 c = gemmW(fbhi, fblo, img + 0*SLAB, W2, 0, use_img, tm, tn, lane);
        __syncthreads();   // all A-frag reads of h1 complete
        const int col = tn*32 + (lane & 31);
        const float bb = b2[col];
        const int rbase = tm*32 + 4*(lane >> 5);
        #pragma unroll
        for (int r = 0; r < 16; ++r){
            const int row = rbase + (r & 3) + 8*(r >> 2);
            float v = elu1(c[r] + bb);
            short h = bf_hi(v);
            fbhi[row*KP + col] = h;
            fblo[row*KP + col] = bf_hi(v - bf_f(h));
        }
    }
    __syncthreads();

    // ==== 3 EdgeConv layers ====
    for (int layer = 0; layer < 3; ++layer){
        // -- squared norms from hi/lo --
        if (tid < 256){
            const int row = tid >> 2, q = tid & 3;
            float s = 0.f;
            #pragma unroll
            for (int b = 0; b < 4; ++b){
                bf16x8 hv = *(const bf16x8*)(fbhi + row*KP + q*32 + b*8);
                bf16x8 lv = *(const bf16x8*)(fblo + row*KP + q*32 + b*8);
                #pragma unroll
                for (int j = 0; j < 8; ++j){
                    float v = bf_f(hv[j]) + bf_f(lv[j]);
                    s += v*v;
                }
            }
            s += __shfl_xor(s, 1, 64);
            s += __shfl_xor(s, 2, 64);
            if (q == 0) sq[row] = s;
        }
        __syncthreads();

        // -- pairwise distances via MFMA 16x16x32 (hi/lo 3-pass), 2 tiles/wave --
        {
            f32x4 dc0, dc1;
            #pragma unroll
            for (int i = 0; i < 4; ++i){ dc0[i] = 0.f; dc1[i] = 0.f; }
            const int t0 = wv*2, t1 = wv*2 + 1;
            const int tm0 = t0 >> 2, tn0 = t0 & 3;
            const int tm1 = t1 >> 2, tn1 = t1 & 3;
            const int rA0 = tm0*16 + (lane & 15), rB0 = tn0*16 + (lane & 15);
            const int rA1 = tm1*16 + (lane & 15), rB1 = tn1*16 + (lane & 15);
            const int ko  = (lane >> 4) * 8;
            #pragma unroll
            for (int ks = 0; ks < 4; ++ks){
                bf16x8 ah0 = *(const bf16x8*)(fbhi + rA0*KP + ks*32 + ko);
                bf16x8 al0 = *(const bf16x8*)(fblo + rA0*KP + ks*32 + ko);
                bf16x8 bh0 = *(const bf16x8*)(fbhi + rB0*KP + ks*32 + ko);
                bf16x8 bl0 = *(const bf16x8*)(fblo + rB0*KP + ks*32 + ko);
                dc0 = __builtin_amdgcn_mfma_f32_16x16x32_bf16(ah0, bh0, dc0, 0,0,0);
                dc0 = __builtin_amdgcn_mfma_f32_16x16x32_bf16(ah0, bl0, dc0, 0,0,0);
                dc0 = __builtin_amdgcn_mfma_f32_16x16x32_bf16(al0, bh0, dc0, 0,0,0);
                bf16x8 ah1 = *(const bf16x8*)(fbhi + rA1*KP + ks*32 + ko);
                bf16x8 al1 = *(const bf16x8*)(fblo + rA1*KP + ks*32 + ko);
                bf16x8 bh1 = *(const bf16x8*)(fbhi + rB1*KP + ks*32 + ko);
                bf16x8 bl1 = *(const bf16x8*)(fblo + rB1*KP + ks*32 + ko);
                dc1 = __builtin_amdgcn_mfma_f32_16x16x32_bf16(ah1, bh1, dc1, 0,0,0);
                dc1 = __builtin_amdgcn_mfma_f32_16x16x32_bf16(ah1, bl1, dc1, 0,0,0);
                dc1 = __builtin_amdgcn_mfma_f32_16x16x32_bf16(al1, bh1, dc1, 0,0,0);
            }
            #pragma unroll
            for (int e = 0; e < 4; ++e){
                const int ra = tm0*16 + (lane >> 4)*4 + e, ca = tn0*16 + (lane & 15);
                dmat[ra*DP + ca] = sq[ra] + sq[ca] - 2.f*dc0[e];
                const int rb = tm1*16 + (lane >> 4)*4 + e, cb = tn1*16 + (lane & 15);
                dmat[rb*DP + cb] = sq[rb] + sq[cb] - 2.f*dc1[e];
            }
        }
        __syncthreads();

        // -- kNN membership via rank counting (ties -> lower index) --
        {
            for (int p = 0; p < 8; ++p){
                const int r = wv*8 + p;
                const float dm = dmat[r*DP + lane];
                float4 rv[16];
                #pragma unroll
                for (int q = 0; q < 16; ++q) rv[q] = *(const float4*)(dmat + r*DP + q*4);
                int rank = 0;
                #pragma unroll
                for (int q = 0; q < 16; ++q){
                    const int m0 = q*4;
                    rank += (rv[q].x < dm) || (rv[q].x == dm && (m0+0) < lane);
                    rank += (rv[q].y < dm) || (rv[q].y == dm && (m0+1) < lane);
                    rank += (rv[q].z < dm) || (rv[q].z == dm && (m0+2) < lane);
                    rank += (rv[q].w < dm) || (rv[q].w == dm && (m0+3) < lane);
                }
                const unsigned long long mask = __ballot(rank < KK);
                if (rank < KK){
                    const int c = __popcll(mask & ((1ULL << lane) - 1ULL));
                    knn[r*KK + c] = lane;
                }
            }
        }
        __syncthreads();   // dmat reads complete -> Vbuf may be overwritten

        // -- V GEMM first; write V to Vbuf immediately (only one f32x16 live) --
        {
            f32x16 vc = gemmW(fbhi, fblo, img + 2*SLAB, Wc, HID, use_img, tm, tn, lane);
            const int col = tn*32 + (lane & 31);
            const int rbase = tm*32 + 4*(lane >> 5);
            #pragma unroll
            for (int r = 0; r < 16; ++r){
                const int row = rbase + (r & 3) + 8*(r >> 2);
                Vbuf[row*FP + col] = vc[r];
            }
        }
        // -- U GEMM; barrier before overwriting features (A-operand) --
        {
            f32x16 uc = gemmW(fbhi, fblo, img + 1*SLAB, Wc, 0, use_img, tm, tn, lane);
            __syncthreads();   // all feature-frag reads complete
            const int col = tn*32 + (lane & 31);
            const int rbase = tm*32 + 4*(lane >> 5);
            #pragma unroll
            for (int r = 0; r < 16; ++r){
                const int row = rbase + (r & 3) + 8*(r >> 2);
                float u = uc[r];
                short h = bf_hi(u);
                fbhi[row*KP + col] = h;
                fblo[row*KP + col] = bf_hi(u - bf_f(h));
            }
        }
        __syncthreads();

        // -- combine: feat[n,h] = elu(U - V_self + bc + max_k V[knn]) -> hi/lo in place --
        {
            float4 bcv = *(const float4*)(bc + h0);
            #pragma unroll
            for (int r = 0; r < 4; ++r){
                const int n = n0 + r;
                float4 mx = make_float4(-1e30f, -1e30f, -1e30f, -1e30f);
                for (int k = 0; k < KK; ++k){
                    int j = knn[n*KK + k];
                    float4 v = *(const float4*)(Vbuf + j*FP + h0);
                    mx.x = fmaxf(mx.x, v.x); mx.y = fmaxf(mx.y, v.y);
                    mx.z = fmaxf(mx.z, v.z); mx.w = fmaxf(mx.w, v.w);
                }
                float4 vn = *(const float4*)(Vbuf + n*FP + h0);
                short4 uh = *(const short4*)(fbhi + n*KP + h0);
                short4 ul = *(const short4*)(fblo + n*KP + h0);
                float o0 = elu1(bf_f(uh.x) + bf_f(ul.x) - vn.x + bcv.x + mx.x);
                float o1 = elu1(bf_f(uh.y) + bf_f(ul.y) - vn.y + bcv.y + mx.y);
                float o2 = elu1(bf_f(uh.z) + bf_f(ul.z) - vn.z + bcv.z + mx.z);
                float o3 = elu1(bf_f(uh.w) + bf_f(ul.w) - vn.w + bcv.w + mx.w);
                short4 nh, nl;
                nh.x = bf_hi(o0); nl.x = bf_hi(o0 - bf_f(nh.x));
                nh.y = bf_hi(o1); nl.y = bf_hi(o1 - bf_f(nh.y));
                nh.z = bf_hi(o2); nl.z = bf_hi(o2 - bf_f(nh.z));
                nh.w = bf_hi(o3); nl.w = bf_hi(o3 - bf_f(nh.w));
                *(short4*)(fbhi + n*KP + h0) = nh;
                *(short4*)(fblo + n*KP + h0) = nl;
            }
        }
        __syncthreads();
    }

    // ==== pooling + head (scratch aliased into Vbuf, dead now) ====
    float* pooled = Vbuf;            // 128
    float* red    = Vbuf + 128;      // 512
    float* hr1    = Vbuf + 640;      // 64
    float* hr2    = Vbuf + 704;      // 32
    float* hr3    = Vbuf + 736;      // 32

    {
        const int pq = tid >> 7, ch = tid & 127;
        float s = 0.f;
        for (int n = pq*16; n < pq*16 + 16; ++n)
            s += bf_f(fbhi[n*KP + ch]) + bf_f(fblo[n*KP + ch]);
        red[pq*HID + ch] = s;
    }
    __syncthreads();
    if (tid < HID) pooled[tid] = red[tid] + red[HID + tid] + red[2*HID + tid] + red[3*HID + tid];
    __syncthreads();
    if (tid < 256){
        const int o = tid & 63, part = tid >> 6;
        float s = 0.f;
        for (int f = part*32; f < part*32 + 32; ++f) s += pooled[f] * Wo1[f*64 + o];
        red[part*64 + o] = s;
    }
    __syncthreads();
    if (tid < 64) hr1[tid] = elu1(bo1[tid] + red[tid] + red[64+tid] + red[128+tid] + red[192+tid]);
    __syncthreads();
    if (tid < 128){
        const int o = tid & 31, part = tid >> 5;
        float s = 0.f;
        for (int f = part*16; f < part*16 + 16; ++f) s += hr1[f] * Wo2[f*32 + o];
        red[part*32 + o] = s;
    }
    __syncthreads();
    if (tid < 32) hr2[tid] = elu1(bo2[tid] + red[tid] + red[32+tid] + red[64+tid] + red[96+tid]);
    __syncthreads();
    if (tid < 32){
        float a = bo3[tid];
        for (int f = 0; f < 32; ++f) a += hr2[f] * Wo3[f*32 + tid];
        hr3[tid] = elu1(a);
    }
    __syncthreads();
    if (tid < 8){
        float a = bo4[tid];
        for (int f = 0; f < 32; ++f) a += hr3[f] * Wo4[f*8 + tid];
        out[g*8 + tid] = a;
    }
}

extern "C" void kernel_launch(void* const* d_in, const int* in_sizes, int n_in,
                              void* d_out, int out_size, void* d_ws, size_t ws_size,
                              hipStream_t stream) {
    short* img = (short*)d_ws;
    const int use_img = (ws_size >= (size_t)IMG_BYTES) ? 1 : 0;
    if (use_img) {
        const int total = 3*4*8*64;   // 6144 threads
        prep_kernel<<<(total + 255)/256, 256, 0, stream>>>(
            (const float*)d_in[4], (const float*)d_in[6], img);
    }
    dgcnn_kernel<<<NG, 512, 0, stream>>>(
        (const float*)d_in[0],
        (const float*)d_in[2],  (const float*)d_in[3],
        (const float*)d_in[4],  (const float*)d_in[5],
        (const float*)d_in[6],  (const float*)d_in[7],
        (const float*)d_in[8],  (const float*)d_in[9],
        (const float*)d_in[10], (const float*)d_in[11],
        (const float*)d_in[12], (const float*)d_in[13],
        (const float*)d_in[14], (const float*)d_in[15],
        img, use_img,
        (float*)d_out);
}

// Round 6
// 100.178 us; speedup vs baseline: 1.0297x; 1.0297x over previous
//
#include <hip/hip_runtime.h>
#include <hip/hip_bf16.h>
#include <math.h>

#define NG  256
#define NN  64
#define KK  24
#define HID 128
#define KP  136   // bf16 LDS row stride (shorts): 272B
#define FP  132   // fp32 LDS row stride (floats)
#define DP  68    // dmat row stride (floats)
#define FRAG 512                 // shorts per fragment (64 lanes x 8)
#define SLAB (4*8*2*FRAG)        // 32768 shorts per weight slab (tn x ks x hl x frag)
#define IMG_BYTES (3*SLAB*2)     // 196608 B

typedef __attribute__((ext_vector_type(8)))  short bf16x8;
typedef __attribute__((ext_vector_type(4)))  float f32x4;
typedef __attribute__((ext_vector_type(16))) float f32x16;

__device__ __forceinline__ float elu1(float x){ return x > 0.f ? x : (expf(x)-1.f); }

__device__ __forceinline__ short bf_hi(float x){
    __hip_bfloat16 h = __float2bfloat16(x);
    return *(short*)&h;
}
__device__ __forceinline__ float bf_f(short s){
    __hip_bfloat16 h = *(__hip_bfloat16*)&s;
    return __bfloat162float(h);
}

// ---- prep: weights -> MFMA-fragment-ordered bf16 hi/lo images in d_ws ----
// addr(s,tn,ks,hl,lane,j) = s*SLAB + ((tn*8+ks)*2+hl)*FRAG + lane*8 + j
// value = W[k][n], n = tn*32+(lane&31), k = ks*16+(lane>>5)*8+j
// s=0: W2 ; s=1: Wc[0:128) (U) ; s=2: Wc[128:256) (V)
extern "C" __global__ void prep_kernel(const float* __restrict__ W2,
                                       const float* __restrict__ Wc,
                                       short* __restrict__ img)
{
    int t = blockIdx.x * 256 + threadIdx.x;    // (s,tn,ks,lane)
    if (t >= 3*4*8*64) return;
    const int lane = t & 63;
    const int ks   = (t >> 6) & 7;
    const int tn   = (t >> 9) & 3;
    const int s    = t >> 11;
    const int n     = tn*32 + (lane & 31);
    const int kbase = ks*16 + (lane >> 5)*8;
    bf16x8 hv, lv;
    #pragma unroll
    for (int j = 0; j < 8; ++j){
        const int k = kbase + j;
        float w = (s == 0) ? W2[k*HID + n]
                : (s == 1) ? Wc[k*HID + n]
                           : Wc[(k + HID)*HID + n];
        short h = bf_hi(w);
        hv[j] = h;
        lv[j] = bf_hi(w - bf_f(h));
    }
    short* dst = img + s*SLAB + ((tn*8 + ks)*2)*FRAG + lane*8;
    *(bf16x8*)(dst)        = hv;
    *(bf16x8*)(dst + FRAG) = lv;
}

// 32x32-tile 3-pass GEMM: A = features (LDS hi/lo), B = weights (global frag img, or gather fallback)
__device__ __forceinline__ f32x16 gemmW(const short* __restrict__ fbhi,
                                        const short* __restrict__ fblo,
                                        const short* __restrict__ imgSlab,
                                        const float* __restrict__ Wg, int rowoff,
                                        int use_img, int tm, int tn, int lane)
{
    f32x16 c;
    #pragma unroll
    for (int i = 0; i < 16; ++i) c[i] = 0.f;
    const int arow = tm*32 + (lane & 31);
    const int ko   = (lane >> 5) * 8;
    const int col  = tn*32 + (lane & 31);
    #pragma unroll
    for (int ks = 0; ks < 8; ++ks){
        bf16x8 ah = *(const bf16x8*)(fbhi + arow*KP + ks*16 + ko);
        bf16x8 al = *(const bf16x8*)(fblo + arow*KP + ks*16 + ko);
        bf16x8 bh, bl;
        if (use_img){
            const short* p = imgSlab + ((tn*8 + ks)*2)*FRAG + lane*8;
            bh = *(const bf16x8*)(p);
            bl = *(const bf16x8*)(p + FRAG);
        } else {
            #pragma unroll
            for (int j = 0; j < 8; ++j){
                float w = Wg[(rowoff + ks*16 + ko + j)*HID + col];
                short h = bf_hi(w);
                bh[j] = h;
                bl[j] = bf_hi(w - bf_f(h));
            }
        }
        c = __builtin_amdgcn_mfma_f32_32x32x16_bf16(ah, bh, c, 0,0,0);
        c = __builtin_amdgcn_mfma_f32_32x32x16_bf16(ah, bl, c, 0,0,0);
        c = __builtin_amdgcn_mfma_f32_32x32x16_bf16(al, bh, c, 0,0,0);
    }
    return c;
}

extern "C" __global__ void
__attribute__((amdgpu_flat_work_group_size(512, 512), amdgpu_waves_per_eu(2, 2)))
dgcnn_kernel(const float* __restrict__ x_pf,
             const float* __restrict__ W1, const float* __restrict__ b1,
             const float* __restrict__ W2, const float* __restrict__ b2,
             const float* __restrict__ Wc, const float* __restrict__ bc,
             const float* __restrict__ Wo1, const float* __restrict__ bo1,
             const float* __restrict__ Wo2, const float* __restrict__ bo2,
             const float* __restrict__ Wo3, const float* __restrict__ bo3,
             const float* __restrict__ Wo4, const float* __restrict__ bo4,
             const short* __restrict__ img, int use_img,
             float* __restrict__ out)
{
    __shared__ __align__(16) short fbhi[NN*KP];   // 17408 B: features hi / then U hi
    __shared__ __align__(16) short fblo[NN*KP];   // 17408 B: features lo / then U lo
    __shared__ __align__(16) float Vbuf[NN*FP];   // 33792 B: dmat early, V fp32 late, head scratch
    __shared__ int   knn[NN*KK];                  // 6144 B
    __shared__ float sq[NN];                      // 256 B
    // total 75008 B

    const int tid  = threadIdx.x;
    const int g    = blockIdx.x;
    const int lane = tid & 63;
    const int wv   = tid >> 6;          // 0..7
    const int hq   = tid & 31;
    const int ngp  = tid >> 5;          // 0..15
    const int h0   = hq * 4;
    const int n0   = ngp * 4;
    const int tm   = wv & 1;
    const int tn   = wv >> 1;

    float* dmat = Vbuf;                 // 64 x DP inside Vbuf (dead before V written)

    if (tid < NN) out[NG*8 + g*NN + tid] = (float)g;

    // ---- W1: h1 = elu(x@W1+b1) -> hi/lo directly ----
    {
        float acc[4][4];
        float4 bv = *(const float4*)(b1 + h0);
        #pragma unroll
        for (int r = 0; r < 4; ++r){ acc[r][0]=bv.x; acc[r][1]=bv.y; acc[r][2]=bv.z; acc[r][3]=bv.w; }
        #pragma unroll
        for (int f = 0; f < 15; ++f){
            float4 w = *(const float4*)(W1 + f*HID + h0);
            #pragma unroll
            for (int r = 0; r < 4; ++r){
                float xv = x_pf[g*NN*15 + (n0 + r)*15 + f];
                acc[r][0] += xv*w.x; acc[r][1] += xv*w.y;
                acc[r][2] += xv*w.z; acc[r][3] += xv*w.w;
            }
        }
        #pragma unroll
        for (int r = 0; r < 4; ++r){
            short4 hv, lv;
            float v0 = elu1(acc[r][0]), v1 = elu1(acc[r][1]), v2 = elu1(acc[r][2]), v3 = elu1(acc[r][3]);
            hv.x = bf_hi(v0); lv.x = bf_hi(v0 - bf_f(hv.x));
            hv.y = bf_hi(v1); lv.y = bf_hi(v1 - bf_f(hv.y));
            hv.z = bf_hi(v2); lv.z = bf_hi(v2 - bf_f(hv.z));
            hv.w = bf_hi(v3); lv.w = bf_hi(v3 - bf_f(hv.w));
            *(short4*)(fbhi + (n0 + r)*KP + h0) = hv;
            *(short4*)(fblo + (n0 + r)*KP + h0) = lv;
        }
    }
    __syncthreads();

    // ---- W2 GEMM: feat = elu(h1@W2 + b2) ----
    {
        f32x16 c = gemmW(fbhi, fblo, img + 0*SLAB, W2, 0, use_img, tm, tn, lane);
        __syncthreads();   // all A-frag reads of h1 complete
        const int col = tn*32 + (lane & 31);
        const float bb = b2[col];
        const int rbase = tm*32 + 4*(lane >> 5);
        #pragma unroll
        for (int r = 0; r < 16; ++r){
            const int row = rbase + (r & 3) + 8*(r >> 2);
            float v = elu1(c[r] + bb);
            short h = bf_hi(v);
            fbhi[row*KP + col] = h;
            fblo[row*KP + col] = bf_hi(v - bf_f(h));
        }
    }
    __syncthreads();

    // ==== 3 EdgeConv layers ====
    for (int layer = 0; layer < 3; ++layer){
        // -- squared norms from hi/lo --
        if (tid < 256){
            const int row = tid >> 2, q = tid & 3;
            float s = 0.f;
            #pragma unroll
            for (int b = 0; b < 4; ++b){
                bf16x8 hv = *(const bf16x8*)(fbhi + row*KP + q*32 + b*8);
                bf16x8 lv = *(const bf16x8*)(fblo + row*KP + q*32 + b*8);
                #pragma unroll
                for (int j = 0; j < 8; ++j){
                    float v = bf_f(hv[j]) + bf_f(lv[j]);
                    s += v*v;
                }
            }
            s += __shfl_xor(s, 1, 64);
            s += __shfl_xor(s, 2, 64);
            if (q == 0) sq[row] = s;
        }
        __syncthreads();

        // -- pairwise distances via MFMA 16x16x32 (hi/lo 3-pass), 2 tiles/wave --
        {
            f32x4 dc0, dc1;
            #pragma unroll
            for (int i = 0; i < 4; ++i){ dc0[i] = 0.f; dc1[i] = 0.f; }
            const int t0 = wv*2, t1 = wv*2 + 1;
            const int tm0 = t0 >> 2, tn0 = t0 & 3;
            const int tm1 = t1 >> 2, tn1 = t1 & 3;
            const int rA0 = tm0*16 + (lane & 15), rB0 = tn0*16 + (lane & 15);
            const int rA1 = tm1*16 + (lane & 15), rB1 = tn1*16 + (lane & 15);
            const int ko  = (lane >> 4) * 8;
            #pragma unroll
            for (int ks = 0; ks < 4; ++ks){
                bf16x8 ah0 = *(const bf16x8*)(fbhi + rA0*KP + ks*32 + ko);
                bf16x8 al0 = *(const bf16x8*)(fblo + rA0*KP + ks*32 + ko);
                bf16x8 bh0 = *(const bf16x8*)(fbhi + rB0*KP + ks*32 + ko);
                bf16x8 bl0 = *(const bf16x8*)(fblo + rB0*KP + ks*32 + ko);
                dc0 = __builtin_amdgcn_mfma_f32_16x16x32_bf16(ah0, bh0, dc0, 0,0,0);
                dc0 = __builtin_amdgcn_mfma_f32_16x16x32_bf16(ah0, bl0, dc0, 0,0,0);
                dc0 = __builtin_amdgcn_mfma_f32_16x16x32_bf16(al0, bh0, dc0, 0,0,0);
                bf16x8 ah1 = *(const bf16x8*)(fbhi + rA1*KP + ks*32 + ko);
                bf16x8 al1 = *(const bf16x8*)(fblo + rA1*KP + ks*32 + ko);
                bf16x8 bh1 = *(const bf16x8*)(fbhi + rB1*KP + ks*32 + ko);
                bf16x8 bl1 = *(const bf16x8*)(fblo + rB1*KP + ks*32 + ko);
                dc1 = __builtin_amdgcn_mfma_f32_16x16x32_bf16(ah1, bh1, dc1, 0,0,0);
                dc1 = __builtin_amdgcn_mfma_f32_16x16x32_bf16(ah1, bl1, dc1, 0,0,0);
                dc1 = __builtin_amdgcn_mfma_f32_16x16x32_bf16(al1, bh1, dc1, 0,0,0);
            }
            #pragma unroll
            for (int e = 0; e < 4; ++e){
                const int ra = tm0*16 + (lane >> 4)*4 + e, ca = tn0*16 + (lane & 15);
                dmat[ra*DP + ca] = sq[ra] + sq[ca] - 2.f*dc0[e];
                const int rb = tm1*16 + (lane >> 4)*4 + e, cb = tn1*16 + (lane & 15);
                dmat[rb*DP + cb] = sq[rb] + sq[cb] - 2.f*dc1[e];
            }
        }
        __syncthreads();

        // -- kNN membership via rank counting (ties -> lower index) --
        {
            for (int p = 0; p < 8; ++p){
                const int r = wv*8 + p;
                const float dm = dmat[r*DP + lane];
                float4 rv[16];
                #pragma unroll
                for (int q = 0; q < 16; ++q) rv[q] = *(const float4*)(dmat + r*DP + q*4);
                int rank = 0;
                #pragma unroll
                for (int q = 0; q < 16; ++q){
                    const int m0 = q*4;
                    rank += (rv[q].x < dm) || (rv[q].x == dm && (m0+0) < lane);
                    rank += (rv[q].y < dm) || (rv[q].y == dm && (m0+1) < lane);
                    rank += (rv[q].z < dm) || (rv[q].z == dm && (m0+2) < lane);
                    rank += (rv[q].w < dm) || (rv[q].w == dm && (m0+3) < lane);
                }
                const unsigned long long mask = __ballot(rank < KK);
                if (rank < KK){
                    const int c = __popcll(mask & ((1ULL << lane) - 1ULL));
                    knn[r*KK + c] = lane;
                }
            }
        }
        __syncthreads();   // dmat reads complete -> Vbuf may be overwritten

        // -- V GEMM first; write V to Vbuf immediately (only one f32x16 live) --
        {
            f32x16 vc = gemmW(fbhi, fblo, img + 2*SLAB, Wc, HID, use_img, tm, tn, lane);
            const int col = tn*32 + (lane & 31);
            const int rbase = tm*32 + 4*(lane >> 5);
            #pragma unroll
            for (int r = 0; r < 16; ++r){
                const int row = rbase + (r & 3) + 8*(r >> 2);
                Vbuf[row*FP + col] = vc[r];
            }
        }
        // pin scheduling: do not hoist U-GEMM loads above the V writes
        __builtin_amdgcn_sched_barrier(0);
        // -- U GEMM; barrier before overwriting features (A-operand) --
        {
            f32x16 uc = gemmW(fbhi, fblo, img + 1*SLAB, Wc, 0, use_img, tm, tn, lane);
            __syncthreads();   // all feature-frag reads complete
            const int col = tn*32 + (lane & 31);
            const int rbase = tm*32 + 4*(lane >> 5);
            #pragma unroll
            for (int r = 0; r < 16; ++r){
                const int row = rbase + (r & 3) + 8*(r >> 2);
                float u = uc[r];
                short h = bf_hi(u);
                fbhi[row*KP + col] = h;
                fblo[row*KP + col] = bf_hi(u - bf_f(h));
            }
        }
        __syncthreads();

        // -- combine: feat[n,h] = elu(U - V_self + bc + max_k V[knn]) -> hi/lo in place --
        {
            float4 bcv = *(const float4*)(bc + h0);
            #pragma unroll
            for (int r = 0; r < 4; ++r){
                const int n = n0 + r;
                float4 mx = make_float4(-1e30f, -1e30f, -1e30f, -1e30f);
                for (int k = 0; k < KK; ++k){
                    int j = knn[n*KK + k];
                    float4 v = *(const float4*)(Vbuf + j*FP + h0);
                    mx.x = fmaxf(mx.x, v.x); mx.y = fmaxf(mx.y, v.y);
                    mx.z = fmaxf(mx.z, v.z); mx.w = fmaxf(mx.w, v.w);
                }
                float4 vn = *(const float4*)(Vbuf + n*FP + h0);
                short4 uh = *(const short4*)(fbhi + n*KP + h0);
                short4 ul = *(const short4*)(fblo + n*KP + h0);
                float o0 = elu1(bf_f(uh.x) + bf_f(ul.x) - vn.x + bcv.x + mx.x);
                float o1 = elu1(bf_f(uh.y) + bf_f(ul.y) - vn.y + bcv.y + mx.y);
                float o2 = elu1(bf_f(uh.z) + bf_f(ul.z) - vn.z + bcv.z + mx.z);
                float o3 = elu1(bf_f(uh.w) + bf_f(ul.w) - vn.w + bcv.w + mx.w);
                short4 nh, nl;
                nh.x = bf_hi(o0); nl.x = bf_hi(o0 - bf_f(nh.x));
                nh.y = bf_hi(o1); nl.y = bf_hi(o1 - bf_f(nh.y));
                nh.z = bf_hi(o2); nl.z = bf_hi(o2 - bf_f(nh.z));
                nh.w = bf_hi(o3); nl.w = bf_hi(o3 - bf_f(nh.w));
                *(short4*)(fbhi + n*KP + h0) = nh;
                *(short4*)(fblo + n*KP + h0) = nl;
            }
        }
        __syncthreads();
    }

    // ==== pooling + head (scratch aliased into Vbuf, dead now) ====
    float* pooled = Vbuf;            // 128
    float* red    = Vbuf + 128;      // 512
    float* hr1    = Vbuf + 640;      // 64
    float* hr2    = Vbuf + 704;      // 32
    float* hr3    = Vbuf + 736;      // 32

    {
        const int pq = tid >> 7, ch = tid & 127;
        float s = 0.f;
        for (int n = pq*16; n < pq*16 + 16; ++n)
            s += bf_f(fbhi[n*KP + ch]) + bf_f(fblo[n*KP + ch]);
        red[pq*HID + ch] = s;
    }
    __syncthreads();
    if (tid < HID) pooled[tid] = red[tid] + red[HID + tid] + red[2*HID + tid] + red[3*HID + tid];
    __syncthreads();
    if (tid < 256){
        const int o = tid & 63, part = tid >> 6;
        float s = 0.f;
        for (int f = part*32; f < part*32 + 32; ++f) s += pooled[f] * Wo1[f*64 + o];
        red[part*64 + o] = s;
    }
    __syncthreads();
    if (tid < 64) hr1[tid] = elu1(bo1[tid] + red[tid] + red[64+tid] + red[128+tid] + red[192+tid]);
    __syncthreads();
    if (tid < 128){
        const int o = tid & 31, part = tid >> 5;
        float s = 0.f;
        for (int f = part*16; f < part*16 + 16; ++f) s += hr1[f] * Wo2[f*32 + o];
        red[part*32 + o] = s;
    }
    __syncthreads();
    if (tid < 32) hr2[tid] = elu1(bo2[tid] + red[tid] + red[32+tid] + red[64+tid] + red[96+tid]);
    __syncthreads();
    if (tid < 32){
        float a = bo3[tid];
        for (int f = 0; f < 32; ++f) a += hr2[f] * Wo3[f*32 + tid];
        hr3[tid] = elu1(a);
    }
    __syncthreads();
    if (tid < 8){
        float a = bo4[tid];
        for (int f = 0; f < 32; ++f) a += hr3[f] * Wo4[f*8 + tid];
        out[g*8 + tid] = a;
    }
}

extern "C" void kernel_launch(void* const* d_in, const int* in_sizes, int n_in,
                              void* d_out, int out_size, void* d_ws, size_t ws_size,
                              hipStream_t stream) {
    short* img = (short*)d_ws;
    const int use_img = (ws_size >= (size_t)IMG_BYTES) ? 1 : 0;
    if (use_img) {
        const int total = 3*4*8*64;   // 6144 threads
        prep_kernel<<<(total + 255)/256, 256, 0, stream>>>(
            (const float*)d_in[4], (const float*)d_in[6], img);
    }
    dgcnn_kernel<<<NG, 512, 0, stream>>>(
        (const float*)d_in[0],
        (const float*)d_in[2],  (const float*)d_in[3],
        (const float*)d_in[4],  (const float*)d_in[5],
        (const float*)d_in[6],  (const float*)d_in[7],
        (const float*)d_in[8],  (const float*)d_in[9],
        (const float*)d_in[10], (const float*)d_in[11],
        (const float*)d_in[12], (const float*)d_in[13],
        (const float*)d_in[14], (const float*)d_in[15],
        img, use_img,
        (float*)d_out);
}